// Round 12
// baseline (238.923 us; speedup 1.0000x reference)
//
#include <hip/hip_runtime.h>
#include <hip/hip_fp16.h>

static constexpr int NN  = 10000;    // nodes
static constexpr int NE  = 640000;   // edges
static constexpr int INC = 128;
static constexpr int HIDC = 256;
static constexpr int OUTC = 128;
static constexpr int CAP = 128;      // ELL row capacity (max in-degree ~104)

static constexpr int FB = 128;       // fill/count slices (5000 edges each)
static constexpr int CB = 64;        // csum slices (10000 edges each)
static constexpr int NP = 10240;     // padded node stride
static constexpr int AB = 2500;      // agg blocks (4 nodes each)
static constexpr int GB = 256;       // gemm blocks
static constexpr int NG = 625;       // 16-node groups

// k_front block ranges: [0,128) count | [128,160) W1T+init | [160,200) scan
// | [200,328) fill | [328,392) csum | [392,456) xh.  456 blocks total — ALL
// co-resident (capacity 512 @ 40KB LDS / 1024 thr) => deadlock impossible.
static constexpr int FRONT_B = 456;
// k_back: [0,2500) agg | [2500,2540) csum-reduce | [2540,2796) gemm waiters.
static constexpr int BACK_B = AB + 40 + GB;
static constexpr unsigned SIGS = AB + 40;   // producer signals gemm waits for

// Two-half magic: a uniform 32-bit poison fill v gives slots v|v; K64's
// halves differ, so poison can never satisfy the check. No init required.
static constexpr unsigned long long K64 = 0xAB5E17EDC0FFEE42ull;

typedef _Float16 half8 __attribute__((ext_vector_type(8)));
typedef float f32x4 __attribute__((ext_vector_type(4)));

// ---- workspace layout (bytes) ----
static constexpr size_t OFF_DONE  = 0;          // uint[1]
static constexpr size_t OFF_V     = 64;         // float[256]
static constexpr size_t OFF_CNT64 = 1088;       // uint[64] signal tree
static constexpr size_t OFF_FLAG1 = 1408;       // u64[128] count-done flags
static constexpr size_t OFF_FLAG2 = 2432;       // u64[40]  scan-done flags
static constexpr size_t OFF_CNT   = 2816;       // int[10240]
static constexpr size_t OFF_DINV  = 43776;      // float[10240]
static constexpr size_t OFF_CSUM  = 84736;      // float[10240]
static constexpr size_t OFF_ELL   = 125696;     // ushort[NN*CAP] (j-permuted)
static constexpr size_t OFF_XH    = 2685696;    // half[NN*INC]
static constexpr size_t OFF_XA    = 5245696;    // half[NN*INC]
static constexpr size_t OFF_CPART = 7805696;    // ushort[128*10240]
static constexpr size_t OFF_CSP   = 10427136;   // float[64*10240]
static constexpr size_t OFF_W1T   = 13048576;   // half[256*128]

// Spin-wait on n magic flags. Relaxed polling (no per-poll L2 invalidate —
// the R3 lesson), ONE acquire after satisfied. Wave 0 polls; rest park at
// the barrier.
__device__ __forceinline__ void wait_flags(const unsigned long long* f, int n) {
    if (threadIdx.x < 64) {
        for (;;) {
            bool ok = true;
            for (int i = threadIdx.x; i < n; i += 64)
                ok &= (__hip_atomic_load(&f[i], __ATOMIC_RELAXED,
                                         __HIP_MEMORY_SCOPE_AGENT) == K64);
            if (__all(ok)) break;
            __builtin_amdgcn_s_sleep(8);
        }
        (void)__hip_atomic_load(&f[0], __ATOMIC_ACQUIRE, __HIP_MEMORY_SCOPE_AGENT);
    }
    __syncthreads();
}

__device__ __forceinline__ void signal_flag(unsigned long long* f) {
    __syncthreads();   // drain all threads' stores (vmcnt0 at barrier)
    if (threadIdx.x == 0)
        __hip_atomic_store(f, K64, __ATOMIC_RELEASE, __HIP_MEMORY_SCOPE_AGENT);
}

// ================= K_FRONT: count | W1T+init | scan | fill | csum | xh ======
__global__ __launch_bounds__(1024) void k_front(
    const int* __restrict__ ei, const float* __restrict__ x,
    const float* __restrict__ W1,
    unsigned short* __restrict__ cpart, __half* __restrict__ w1t,
    int* __restrict__ cnt, float* __restrict__ dinv,
    unsigned short* __restrict__ ell, float* __restrict__ cspart,
    __half* __restrict__ xh,
    unsigned long long* __restrict__ flag1, unsigned long long* __restrict__ flag2,
    float* __restrict__ v, unsigned int* __restrict__ done,
    unsigned int* __restrict__ cnt64)
{
    __shared__ int lh[NN];           // 40 KB, reused by count/fill/csum
    int t = threadIdx.x, b = blockIdx.x;

    if (b < FB) {
        // ---- count: LDS histogram of slice b (proven body) ----
        for (int i = t; i < NN; i += 1024) lh[i] = 0;
        __syncthreads();
        int e0 = b * (NE / FB);
        const int4* d4 = (const int4*)(ei + NE + e0);
        for (int k = t; k < (NE / FB) / 4; k += 1024) {
            int4 dd = d4[k];
            atomicAdd(&lh[dd.x], 1);
            atomicAdd(&lh[dd.y], 1);
            atomicAdd(&lh[dd.z], 1);
            atomicAdd(&lh[dd.w], 1);
        }
        __syncthreads();
        for (int i = t; i < NN; i += 1024) cpart[b * NP + i] = (unsigned short)lh[i];
        signal_flag(&flag1[b]);
    } else if (b < FB + 32) {
        // ---- W1^T (proven) + zero v/done/cnt64 for k_back ----
        int gid = (b - FB) * 1024 + t;
        int k = gid & 127, tc = gid >> 7;
        w1t[tc * INC + k] = __float2half(W1[k * HIDC + tc]);
        if (b == FB) {
            if (t < 256) v[t] = 0.f;
            else if (t < 320) cnt64[t - 256] = 0u;
            else if (t == 320) *done = 0u;
        }
    } else if (b < FB + 32 + 40) {
        // ---- scan (proven body; 256 active lanes/block) ----
        wait_flags(flag1, FB);
        if (t < 256) {
            int n = (b - FB - 32) * 256 + t;
            if (n < NN) {
                int run = 0;
#pragma unroll 8
                for (int bb = 0; bb < FB; bb++) {
                    int c = cpart[bb * NP + n];
                    cpart[bb * NP + n] = (unsigned short)run;
                    run += c;
                }
                cnt[n] = run;
                dinv[n] = rsqrtf((float)(1 + run));   // +1 self loop
            }
        }
        signal_flag(&flag2[b - FB - 32]);
    } else if (b < FB + 32 + 40 + FB) {
        // ---- ELL fill (j-permuted, absolute LDS cursor; proven body) ----
        wait_flags(flag2, 40);
        int sb = b - FB - 32 - 40;
        for (int i = t; i < NN; i += 1024) lh[i] = (int)cpart[sb * NP + i];
        __syncthreads();
        int e0 = sb * (NE / FB);
        const int4* s4 = (const int4*)(ei + e0);
        const int4* d4 = (const int4*)(ei + NE + e0);
        for (int k = t; k < (NE / FB) / 4; k += 1024) {
            int4 s = s4[k];
            int4 d = d4[k];
            int ss[4] = {s.x, s.y, s.z, s.w};
            int dd[4] = {d.x, d.y, d.z, d.w};
#pragma unroll
            for (int u = 0; u < 4; u++) {
                int pos = atomicAdd(&lh[dd[u]], 1);   // absolute position
                if (pos < CAP)
                    ell[dd[u] * CAP + (pos & 3) * 32 + (pos >> 2)] = (unsigned short)ss[u];
            }
        }
    } else if (b < FB + 32 + 40 + FB + CB) {
        // ---- csum partials (proven body) ----
        wait_flags(flag2, 40);
        int cb = b - FB - 32 - 40 - FB;
        float* lc = (float*)lh;
        for (int i = t; i < NN; i += 1024) lc[i] = 0.f;
        __syncthreads();
        int e0 = cb * (NE / CB);
        const int4* s4 = (const int4*)(ei + e0);
        const int4* d4 = (const int4*)(ei + NE + e0);
        for (int k = t; k < (NE / CB) / 4; k += 1024) {
            int4 s = s4[k];
            int4 d = d4[k];
            atomicAdd(&lc[s.x], dinv[d.x]);
            atomicAdd(&lc[s.y], dinv[d.y]);
            atomicAdd(&lc[s.z], dinv[d.z]);
            atomicAdd(&lc[s.w], dinv[d.w]);
        }
        __syncthreads();
        for (int i = t; i < NN; i += 1024) cspart[cb * NP + i] = lc[i];
    } else {
        // ---- xh[n,:] = fp16(dinv[n]*X[n,:]); 64 blocks, grid-stride ----
        wait_flags(flag2, 40);
        int gid0 = (b - FB - 32 - 40 - FB - CB) * 1024 + t;
        for (int i4 = gid0; i4 < NN * (INC / 4); i4 += 64 * 1024) {
            float4 vv = ((const float4*)x)[i4];
            float dv = dinv[i4 >> 5];
            __half2 o[2] = {__floats2half2_rn(dv * vv.x, dv * vv.y),
                            __floats2half2_rn(dv * vv.z, dv * vv.w)};
            *(float2*)(xh + i4 * 4) = *(float2*)o;
        }
    }
}

// ================= K_BACK: agg | csum-reduce | gemm(wait) ==================
__global__ __launch_bounds__(256) void k_back(
    const float* __restrict__ x, const __half* __restrict__ xh,
    const float* __restrict__ dinv, const int* __restrict__ cnt,
    const unsigned short* __restrict__ ell, const float* __restrict__ cspart,
    float* __restrict__ csum, __half* __restrict__ xa,
    const __half* __restrict__ w1t, const float* __restrict__ b1,
    float* __restrict__ v, unsigned int* __restrict__ done,
    unsigned int* __restrict__ cnt64,
    const float* __restrict__ W2, const float* __restrict__ b2,
    const float* __restrict__ fcw, const float* __restrict__ fcb,
    float* __restrict__ out)
{
    int b = blockIdx.x, t = threadIdx.x;

    if (b < AB) {
        // ---- aggregation gather (proven R6 body) ----
        int lane = t & 63;
        int n = b * 4 + (t >> 6);
        int g = lane & 15;
        int j = lane >> 4;
        float dn = dinv[n];
        int c = cnt[n];
        int ebase = n * CAP + j * 32;

        uint4 ev0, ev1, ev2, ev3;
        if (c >  0) ev0 = *(const uint4*)(ell + ebase);
        if (c > 32) ev1 = *(const uint4*)(ell + ebase + 8);
        if (c > 64) ev2 = *(const uint4*)(ell + ebase + 16);
        if (c > 96) ev3 = *(const uint4*)(ell + ebase + 24);

        float acc[8];
#pragma unroll
        for (int k = 0; k < 8; k++) acc[k] = 0.f;
        if (j == 0) {
            const float4* x4 = (const float4*)x;
            float4 a = x4[n * 32 + 2 * g];
            float4 c4 = x4[n * 32 + 2 * g + 1];
            acc[0] = dn * a.x;  acc[1] = dn * a.y;  acc[2] = dn * a.z;  acc[3] = dn * a.w;
            acc[4] = dn * c4.x; acc[5] = dn * c4.y; acc[6] = dn * c4.z; acc[7] = dn * c4.w;
        }
        const __half* xg = xh + 8 * g;
#pragma unroll
        for (int it = 0; it < 4; it++) {
            uint4 ev = (it == 0) ? ev0 : (it == 1) ? ev1 : (it == 2) ? ev2 : ev3;
            int i0 = it * 32;
            if (i0 + 32 <= c) {
                unsigned raw[8] = {ev.x & 0xffffu, ev.x >> 16, ev.y & 0xffffu, ev.y >> 16,
                                   ev.z & 0xffffu, ev.z >> 16, ev.w & 0xffffu, ev.w >> 16};
                float4 xv[8];
#pragma unroll
                for (int u = 0; u < 8; u++)
                    xv[u] = *(const float4*)(xg + (int)raw[u] * INC);
#pragma unroll
                for (int u = 0; u < 8; u++) {
                    const __half2* h2 = (const __half2*)&xv[u];
#pragma unroll
                    for (int q = 0; q < 4; q++) {
                        float2 f = __half22float2(h2[q]);
                        acc[2 * q]     += f.x;
                        acc[2 * q + 1] += f.y;
                    }
                }
            } else if (i0 < c) {
                unsigned raw[8] = {ev.x & 0xffffu, ev.x >> 16, ev.y & 0xffffu, ev.y >> 16,
                                   ev.z & 0xffffu, ev.z >> 16, ev.w & 0xffffu, ev.w >> 16};
                int   su[8];
                float ws[8];
                float4 xv[8];
#pragma unroll
                for (int u = 0; u < 8; u++) {
                    int idx = i0 + 4 * u + j;
                    bool act = idx < c;
                    su[u] = act ? (int)raw[u] : n;
                    ws[u] = act ? 1.f : 0.f;
                }
#pragma unroll
                for (int u = 0; u < 8; u++)
                    xv[u] = *(const float4*)(xg + su[u] * INC);
#pragma unroll
                for (int u = 0; u < 8; u++) {
                    const __half2* h2 = (const __half2*)&xv[u];
#pragma unroll
                    for (int q = 0; q < 4; q++) {
                        float2 f = __half22float2(h2[q]);
                        acc[2 * q]     = fmaf(ws[u], f.x, acc[2 * q]);
                        acc[2 * q + 1] = fmaf(ws[u], f.y, acc[2 * q + 1]);
                    }
                }
            }
        }
#pragma unroll
        for (int k = 0; k < 8; k++) {
            acc[k] += __shfl_down(acc[k], 32);
            acc[k] += __shfl_down(acc[k], 16);
        }
        if (j == 0) {
            __half2 o[4];
#pragma unroll
            for (int q = 0; q < 4; q++)
                o[q] = __floats2half2_rn(dn * acc[2 * q], dn * acc[2 * q + 1]);
            *(float4*)(xa + n * INC + 8 * g) = *(float4*)o;
        }
        __syncthreads();   // drain xa stores before the release
        if (t == 0)
            __hip_atomic_fetch_add(&cnt64[b & 63], 1u, __ATOMIC_RELEASE,
                                   __HIP_MEMORY_SCOPE_AGENT);
    } else if (b < AB + 40) {
        // ---- csum partial reduce (proven tail body) ----
        int n = (b - AB) * 256 + t;
        if (n < NN) {
            float s = 0.f;
#pragma unroll
            for (int bb = 0; bb < CB; bb++) s += cspart[bb * NP + n];
            csum[n] = s;
        }
        __syncthreads();
        if (t == 0)
            __hip_atomic_fetch_add(&cnt64[b & 63], 1u, __ATOMIC_RELEASE,
                                   __HIP_MEMORY_SCOPE_AGENT);
    } else {
        // ---- gemm: wait for all 2540 producers via 64-counter sweep ----
        if (t < 64) {
            for (;;) {
                unsigned cc = __hip_atomic_load(&cnt64[t], __ATOMIC_RELAXED,
                                                __HIP_MEMORY_SCOPE_AGENT);
#pragma unroll
                for (int o = 32; o > 0; o >>= 1) cc += __shfl_down(cc, o);
                cc = __shfl(cc, 0);
                if (cc >= SIGS) break;
                __builtin_amdgcn_s_sleep(8);
            }
            (void)__hip_atomic_load(&cnt64[0], __ATOMIC_ACQUIRE,
                                    __HIP_MEMORY_SCOPE_AGENT);
        }
        __syncthreads();

        // ---- proven k_gemm body (gb in [0,256), stride 256, done target 255)
        __shared__ float vloc[HIDC];
        int gb = b - AB - 40;
        int w = t >> 6;
        int lane = t & 63;
        int m = lane & 15;
        int quad = lane >> 4;
        for (int i = t; i < HIDC; i += 256) vloc[i] = 0.f;
        __syncthreads();

        float bcol[4];
#pragma unroll
        for (int tt = 0; tt < 4; tt++) bcol[tt] = b1[w * 64 + tt * 16 + m];

        const half8* xa8 = (const half8*)xa;
        const half8* w8  = (const half8*)w1t;

        for (int gidx = gb; gidx < NG; gidx += GB) {
            int base = gidx * 16;
            f32x4 acc[4] = {{0,0,0,0},{0,0,0,0},{0,0,0,0},{0,0,0,0}};
#pragma unroll
            for (int k0 = 0; k0 < 4; k0++) {
                half8 af = xa8[(base + m) * 16 + k0 * 4 + quad];
#pragma unroll
                for (int tt = 0; tt < 4; tt++) {
                    int col = w * 64 + tt * 16 + m;
                    half8 bf = w8[col * 16 + k0 * 4 + quad];
                    acc[tt] = __builtin_amdgcn_mfma_f32_16x16x32_f16(af, bf, acc[tt], 0, 0, 0);
                }
            }
            float cr[4];
#pragma unroll
            for (int r = 0; r < 4; r++) {
                int n = base + quad * 4 + r;
                float dnn = dinv[n];
                cr[r] = dnn * (dnn + csum[n]);
            }
#pragma unroll
            for (int tt = 0; tt < 4; tt++) {
                float p = 0.f;
#pragma unroll
                for (int r = 0; r < 4; r++)
                    p += cr[r] * fmaxf(acc[tt][r] + bcol[tt], 0.f);
                p += __shfl_down(p, 16);
                p += __shfl_down(p, 32);
                if (lane < 16) vloc[w * 64 + tt * 16 + lane] += p;
            }
        }
        __syncthreads();
        atomicAdd(&v[t], vloc[t]);
        __threadfence();
        __shared__ bool last;
        if (t == 0) {
            unsigned int old = __hip_atomic_fetch_add(done, 1u, __ATOMIC_ACQ_REL,
                                                      __HIP_MEMORY_SCOPE_AGENT);
            last = (old == GB - 1);
        }
        __syncthreads();
        if (!last) return;
        float vt = __hip_atomic_load(&v[t], __ATOMIC_ACQUIRE, __HIP_MEMORY_SCOPE_AGENT);
        __shared__ float red[256];
        float u = 0.f;
#pragma unroll 4
        for (int jj = 0; jj < OUTC; jj++) u = fmaf(W2[t * OUTC + jj], fcw[jj], u);
        float contrib = vt * u * (1.0f / (float)NN);
        if (t < OUTC) contrib += b2[t] * fcw[t];
        red[t] = contrib;
        __syncthreads();
        for (int s = 128; s > 0; s >>= 1) {
            if (t < s) red[t] += red[t + s];
            __syncthreads();
        }
        if (t == 0) out[0] = red[0] + fcb[0];
    }
}

extern "C" void kernel_launch(void* const* d_in, const int* in_sizes, int n_in,
                              void* d_out, int out_size, void* d_ws, size_t ws_size,
                              hipStream_t stream) {
    const float* x   = (const float*)d_in[0];
    const int*   ei  = (const int*)d_in[1];
    const float* W1  = (const float*)d_in[2];
    const float* b1  = (const float*)d_in[3];
    const float* W2  = (const float*)d_in[4];
    const float* b2  = (const float*)d_in[5];
    const float* fcw = (const float*)d_in[6];
    const float* fcb = (const float*)d_in[7];
    float* out = (float*)d_out;

    char* ws = (char*)d_ws;
    unsigned int*       done   = (unsigned int*)(ws + OFF_DONE);
    float*              v      = (float*)(ws + OFF_V);
    unsigned int*       cnt64  = (unsigned int*)(ws + OFF_CNT64);
    unsigned long long* flag1  = (unsigned long long*)(ws + OFF_FLAG1);
    unsigned long long* flag2  = (unsigned long long*)(ws + OFF_FLAG2);
    int*                cnt    = (int*)(ws + OFF_CNT);
    float*              dinv   = (float*)(ws + OFF_DINV);
    float*              csum   = (float*)(ws + OFF_CSUM);
    unsigned short*     ell    = (unsigned short*)(ws + OFF_ELL);
    __half*             xh     = (__half*)(ws + OFF_XH);
    __half*             xa     = (__half*)(ws + OFF_XA);
    unsigned short*     cpart  = (unsigned short*)(ws + OFF_CPART);
    float*              cspart = (float*)(ws + OFF_CSP);
    __half*             w1t    = (__half*)(ws + OFF_W1T);

    k_front<<<FRONT_B, 1024, 0, stream>>>(ei, x, W1, cpart, w1t, cnt, dinv,
                                          ell, cspart, xh, flag1, flag2,
                                          v, done, cnt64);
    k_back<<<BACK_B, 256, 0, stream>>>(x, xh, dinv, cnt, ell, cspart, csum, xa,
                                       w1t, b1, v, done, cnt64,
                                       W2, b2, fcw, fcb, out);
}

// Round 13
// 153.603 us; speedup vs baseline: 1.5555x; 1.5555x over previous
//
#include <hip/hip_runtime.h>
#include <hip/hip_fp16.h>

static constexpr int NN  = 10000;    // nodes
static constexpr int NE  = 640000;   // edges
static constexpr int INC = 128;
static constexpr int HIDC = 256;
static constexpr int OUTC = 128;
static constexpr int CAP = 128;      // ELL row capacity (max in-degree ~104)

static constexpr int FB = 128;       // fill/count slices (5000 edges each)
static constexpr int CB = 64;        // csum slices (10000 edges each)
static constexpr int NP = 10240;     // padded node stride
static constexpr int AB = 2500;      // agg blocks (4 nodes each)
static constexpr int GG = 256;       // gemm blocks
static constexpr int NG = 625;       // 16-node groups

// k_front block ranges: [0,128) count | [128,160) W1T+init | [160,200) scan
// | [200,328) fill | [328,392) csum | [392,456) xh.  456 blocks total — ALL
// co-resident (capacity 512 @ 40KB LDS / 1024 thr) => deadlock impossible.
// Flag signaling at 128/40 scale is proven cheap (R12); 2500-scale release
// signaling costs ~50ns each serialized (R4/R10/R12) and is banned.
static constexpr int FRONT_B = 456;

// Two-half magic: a uniform 32-bit poison fill v gives slots v|v; K64's
// halves differ, so poison can never satisfy the check. No init required.
static constexpr unsigned long long K64 = 0xAB5E17EDC0FFEE42ull;

typedef _Float16 half8 __attribute__((ext_vector_type(8)));
typedef float f32x4 __attribute__((ext_vector_type(4)));

// ---- workspace layout (bytes) ----
static constexpr size_t OFF_DONE  = 0;          // uint[1]
static constexpr size_t OFF_V     = 64;         // float[256]
static constexpr size_t OFF_FLAG1 = 1408;       // u64[128] count-done flags
static constexpr size_t OFF_FLAG2 = 2432;       // u64[40]  scan-done flags
static constexpr size_t OFF_CNT   = 2816;       // int[10240]
static constexpr size_t OFF_DINV  = 43776;      // float[10240]
static constexpr size_t OFF_CSUM  = 84736;      // float[10240]
static constexpr size_t OFF_ELL   = 125696;     // ushort[NN*CAP] (j-permuted)
static constexpr size_t OFF_XH    = 2685696;    // half[NN*INC]
static constexpr size_t OFF_XA    = 5245696;    // half[NN*INC]
static constexpr size_t OFF_CPART = 7805696;    // ushort[128*10240]
static constexpr size_t OFF_CSP   = 10427136;   // float[64*10240]
static constexpr size_t OFF_W1T   = 13048576;   // half[256*128]

// Spin-wait on n magic flags. Relaxed polling (no per-poll L2 invalidate —
// the R3 lesson), ONE acquire after satisfied. Wave 0 polls; rest park.
__device__ __forceinline__ void wait_flags(const unsigned long long* f, int n) {
    if (threadIdx.x < 64) {
        for (;;) {
            bool ok = true;
            for (int i = threadIdx.x; i < n; i += 64)
                ok &= (__hip_atomic_load(&f[i], __ATOMIC_RELAXED,
                                         __HIP_MEMORY_SCOPE_AGENT) == K64);
            if (__all(ok)) break;
            __builtin_amdgcn_s_sleep(8);
        }
        (void)__hip_atomic_load(&f[0], __ATOMIC_ACQUIRE, __HIP_MEMORY_SCOPE_AGENT);
    }
    __syncthreads();
}

__device__ __forceinline__ void signal_flag(unsigned long long* f) {
    __syncthreads();   // drain all threads' stores before the release
    if (threadIdx.x == 0)
        __hip_atomic_store(f, K64, __ATOMIC_RELEASE, __HIP_MEMORY_SCOPE_AGENT);
}

// ================= K_FRONT: count | W1T+init | scan | fill | csum | xh ======
// Byte-identical to the R12-verified kernel (minus dead cnt64 init).
__global__ __launch_bounds__(1024) void k_front(
    const int* __restrict__ ei, const float* __restrict__ x,
    const float* __restrict__ W1,
    unsigned short* __restrict__ cpart, __half* __restrict__ w1t,
    int* __restrict__ cnt, float* __restrict__ dinv,
    unsigned short* __restrict__ ell, float* __restrict__ cspart,
    __half* __restrict__ xh,
    unsigned long long* __restrict__ flag1, unsigned long long* __restrict__ flag2,
    float* __restrict__ v, unsigned int* __restrict__ done)
{
    __shared__ int lh[NN];           // 40 KB, reused by count/fill/csum
    int t = threadIdx.x, b = blockIdx.x;

    if (b < FB) {
        // ---- count: LDS histogram of slice b (proven body) ----
        for (int i = t; i < NN; i += 1024) lh[i] = 0;
        __syncthreads();
        int e0 = b * (NE / FB);
        const int4* d4 = (const int4*)(ei + NE + e0);
        for (int k = t; k < (NE / FB) / 4; k += 1024) {
            int4 dd = d4[k];
            atomicAdd(&lh[dd.x], 1);
            atomicAdd(&lh[dd.y], 1);
            atomicAdd(&lh[dd.z], 1);
            atomicAdd(&lh[dd.w], 1);
        }
        __syncthreads();
        for (int i = t; i < NN; i += 1024) cpart[b * NP + i] = (unsigned short)lh[i];
        signal_flag(&flag1[b]);
    } else if (b < FB + 32) {
        // ---- W1^T (proven) + zero v/done for k_gemm (2 dispatches later) ----
        int gid = (b - FB) * 1024 + t;
        int k = gid & 127, tc = gid >> 7;
        w1t[tc * INC + k] = __float2half(W1[k * HIDC + tc]);
        if (b == FB) {
            if (t < 256) v[t] = 0.f;
            else if (t == 256) *done = 0u;
        }
    } else if (b < FB + 32 + 40) {
        // ---- scan (proven body; 256 active lanes/block) ----
        wait_flags(flag1, FB);
        if (t < 256) {
            int n = (b - FB - 32) * 256 + t;
            if (n < NN) {
                int run = 0;
#pragma unroll 8
                for (int bb = 0; bb < FB; bb++) {
                    int c = cpart[bb * NP + n];
                    cpart[bb * NP + n] = (unsigned short)run;
                    run += c;
                }
                cnt[n] = run;
                dinv[n] = rsqrtf((float)(1 + run));   // +1 self loop
            }
        }
        signal_flag(&flag2[b - FB - 32]);
    } else if (b < FB + 32 + 40 + FB) {
        // ---- ELL fill (j-permuted, absolute LDS cursor; proven body) ----
        wait_flags(flag2, 40);
        int sb = b - FB - 32 - 40;
        for (int i = t; i < NN; i += 1024) lh[i] = (int)cpart[sb * NP + i];
        __syncthreads();
        int e0 = sb * (NE / FB);
        const int4* s4 = (const int4*)(ei + e0);
        const int4* d4 = (const int4*)(ei + NE + e0);
        for (int k = t; k < (NE / FB) / 4; k += 1024) {
            int4 s = s4[k];
            int4 d = d4[k];
            int ss[4] = {s.x, s.y, s.z, s.w};
            int dd[4] = {d.x, d.y, d.z, d.w};
#pragma unroll
            for (int u = 0; u < 4; u++) {
                int pos = atomicAdd(&lh[dd[u]], 1);   // absolute position
                if (pos < CAP)
                    ell[dd[u] * CAP + (pos & 3) * 32 + (pos >> 2)] = (unsigned short)ss[u];
            }
        }
    } else if (b < FB + 32 + 40 + FB + CB) {
        // ---- csum partials (proven body) ----
        wait_flags(flag2, 40);
        int cb = b - FB - 32 - 40 - FB;
        float* lc = (float*)lh;
        for (int i = t; i < NN; i += 1024) lc[i] = 0.f;
        __syncthreads();
        int e0 = cb * (NE / CB);
        const int4* s4 = (const int4*)(ei + e0);
        const int4* d4 = (const int4*)(ei + NE + e0);
        for (int k = t; k < (NE / CB) / 4; k += 1024) {
            int4 s = s4[k];
            int4 d = d4[k];
            atomicAdd(&lc[s.x], dinv[d.x]);
            atomicAdd(&lc[s.y], dinv[d.y]);
            atomicAdd(&lc[s.z], dinv[d.z]);
            atomicAdd(&lc[s.w], dinv[d.w]);
        }
        __syncthreads();
        for (int i = t; i < NN; i += 1024) cspart[cb * NP + i] = lc[i];
    } else {
        // ---- xh[n,:] = fp16(dinv[n]*X[n,:]); 64 blocks, grid-stride ----
        wait_flags(flag2, 40);
        int gid0 = (b - FB - 32 - 40 - FB - CB) * 1024 + t;
        for (int i4 = gid0; i4 < NN * (INC / 4); i4 += 64 * 1024) {
            float4 vv = ((const float4*)x)[i4];
            float dv = dinv[i4 >> 5];
            __half2 o[2] = {__floats2half2_rn(dv * vv.x, dv * vv.y),
                            __floats2half2_rn(dv * vv.z, dv * vv.w)};
            *(float2*)(xh + i4 * 4) = *(float2*)o;
        }
    }
}

// ---- K_AGG (proven R6 body): aggregation gather | csum reduce ----
__global__ __launch_bounds__(256) void k_agg(const float* __restrict__ x,
                                             const __half* __restrict__ xh,
                                             const float* __restrict__ dinv,
                                             const int* __restrict__ cnt,
                                             const unsigned short* __restrict__ ell,
                                             const float* __restrict__ cspart,
                                             float* __restrict__ csum,
                                             __half* __restrict__ xa) {
    int b = blockIdx.x;
    if (b >= AB) {   // csum partial reduce (40 tail blocks)
        int n = (b - AB) * 256 + threadIdx.x;
        if (n < NN) {
            float s = 0.f;
#pragma unroll
            for (int bb = 0; bb < CB; bb++) s += cspart[bb * NP + n];
            csum[n] = s;
        }
        return;
    }
    int lane = threadIdx.x & 63;
    int n = b * 4 + (threadIdx.x >> 6);
    int g = lane & 15;        // 16B chunk of the 256B fp16 row
    int j = lane >> 4;        // neighbor group
    float dn = dinv[n];
    int c = cnt[n];
    int ebase = n * CAP + j * 32;

    uint4 ev0, ev1, ev2, ev3;
    if (c >  0) ev0 = *(const uint4*)(ell + ebase);
    if (c > 32) ev1 = *(const uint4*)(ell + ebase + 8);
    if (c > 64) ev2 = *(const uint4*)(ell + ebase + 16);
    if (c > 96) ev3 = *(const uint4*)(ell + ebase + 24);

    float acc[8];
#pragma unroll
    for (int k = 0; k < 8; k++) acc[k] = 0.f;
    if (j == 0) {             // self loop from fp32 X (outer dn applied at end)
        const float4* x4 = (const float4*)x;
        float4 a = x4[n * 32 + 2 * g];
        float4 c4 = x4[n * 32 + 2 * g + 1];
        acc[0] = dn * a.x;  acc[1] = dn * a.y;  acc[2] = dn * a.z;  acc[3] = dn * a.w;
        acc[4] = dn * c4.x; acc[5] = dn * c4.y; acc[6] = dn * c4.z; acc[7] = dn * c4.w;
    }
    const __half* xg = xh + 8 * g;
#pragma unroll
    for (int it = 0; it < 4; it++) {
        uint4 ev = (it == 0) ? ev0 : (it == 1) ? ev1 : (it == 2) ? ev2 : ev3;
        int i0 = it * 32;
        if (i0 + 32 <= c) {
            unsigned raw[8] = {ev.x & 0xffffu, ev.x >> 16, ev.y & 0xffffu, ev.y >> 16,
                               ev.z & 0xffffu, ev.z >> 16, ev.w & 0xffffu, ev.w >> 16};
            float4 xv[8];
#pragma unroll
            for (int u = 0; u < 8; u++)
                xv[u] = *(const float4*)(xg + (int)raw[u] * INC);
#pragma unroll
            for (int u = 0; u < 8; u++) {
                const __half2* h2 = (const __half2*)&xv[u];
#pragma unroll
                for (int q = 0; q < 4; q++) {
                    float2 f = __half22float2(h2[q]);
                    acc[2 * q]     += f.x;
                    acc[2 * q + 1] += f.y;
                }
            }
        } else if (i0 < c) {
            unsigned raw[8] = {ev.x & 0xffffu, ev.x >> 16, ev.y & 0xffffu, ev.y >> 16,
                               ev.z & 0xffffu, ev.z >> 16, ev.w & 0xffffu, ev.w >> 16};
            int   su[8];
            float ws[8];
            float4 xv[8];
#pragma unroll
            for (int u = 0; u < 8; u++) {
                int idx = i0 + 4 * u + j;
                bool act = idx < c;
                su[u] = act ? (int)raw[u] : n;
                ws[u] = act ? 1.f : 0.f;
            }
#pragma unroll
            for (int u = 0; u < 8; u++)
                xv[u] = *(const float4*)(xg + su[u] * INC);
#pragma unroll
            for (int u = 0; u < 8; u++) {
                const __half2* h2 = (const __half2*)&xv[u];
#pragma unroll
                for (int q = 0; q < 4; q++) {
                    float2 f = __half22float2(h2[q]);
                    acc[2 * q]     = fmaf(ws[u], f.x, acc[2 * q]);
                    acc[2 * q + 1] = fmaf(ws[u], f.y, acc[2 * q + 1]);
                }
            }
        }
    }
#pragma unroll
    for (int k = 0; k < 8; k++) {
        acc[k] += __shfl_down(acc[k], 32);
        acc[k] += __shfl_down(acc[k], 16);
    }
    if (j == 0) {
        __half2 o[4];
#pragma unroll
        for (int q = 0; q < 4; q++)
            o[q] = __floats2half2_rn(dn * acc[2 * q], dn * acc[2 * q + 1]);
        *(float4*)(xa + n * INC + 8 * g) = *(float4*)o;
    }
}

// ---- K_GEMM (proven R6 body): MFMA + weighted-relu reduce + final scalar ----
__global__ __launch_bounds__(256) void k_gemm(const __half* __restrict__ xa,
                                              const __half* __restrict__ w1t,
                                              const float* __restrict__ b1,
                                              const float* __restrict__ dinv,
                                              const float* __restrict__ csum,
                                              float* __restrict__ v,
                                              unsigned int* __restrict__ done,
                                              const float* __restrict__ W2,
                                              const float* __restrict__ b2,
                                              const float* __restrict__ fcw,
                                              const float* __restrict__ fcb,
                                              float* __restrict__ out) {
    __shared__ float vloc[HIDC];
    int t = threadIdx.x;
    int w = t >> 6;           // wave id: owns cols [64w, 64w+64)
    int lane = t & 63;
    int m = lane & 15;
    int quad = lane >> 4;
    for (int i = t; i < HIDC; i += 256) vloc[i] = 0.f;
    __syncthreads();

    float bcol[4];
#pragma unroll
    for (int tt = 0; tt < 4; tt++) bcol[tt] = b1[w * 64 + tt * 16 + m];

    const half8* xa8 = (const half8*)xa;     // 8-half (16B) granules
    const half8* w8  = (const half8*)w1t;

    for (int gidx = blockIdx.x; gidx < NG; gidx += gridDim.x) {
        int base = gidx * 16;
        f32x4 acc[4] = {{0,0,0,0},{0,0,0,0},{0,0,0,0},{0,0,0,0}};
#pragma unroll
        for (int k0 = 0; k0 < 4; k0++) {
            half8 af = xa8[(base + m) * 16 + k0 * 4 + quad];
#pragma unroll
            for (int tt = 0; tt < 4; tt++) {
                int col = w * 64 + tt * 16 + m;
                half8 bf = w8[col * 16 + k0 * 4 + quad];
                acc[tt] = __builtin_amdgcn_mfma_f32_16x16x32_f16(af, bf, acc[tt], 0, 0, 0);
            }
        }
        float cr[4];
#pragma unroll
        for (int r = 0; r < 4; r++) {
            int n = base + quad * 4 + r;
            float dnn = dinv[n];
            cr[r] = dnn * (dnn + csum[n]);
        }
#pragma unroll
        for (int tt = 0; tt < 4; tt++) {
            float p = 0.f;
#pragma unroll
            for (int r = 0; r < 4; r++)
                p += cr[r] * fmaxf(acc[tt][r] + bcol[tt], 0.f);
            p += __shfl_down(p, 16);
            p += __shfl_down(p, 32);
            if (lane < 16) vloc[w * 64 + tt * 16 + lane] += p;  // wave-disjoint cols
        }
    }
    __syncthreads();
    atomicAdd(&v[t], vloc[t]);      // 256 releases: proven-cheap scale
    __threadfence();
    __shared__ bool last;
    if (t == 0) {
        unsigned int old = __hip_atomic_fetch_add(done, 1u, __ATOMIC_ACQ_REL,
                                                  __HIP_MEMORY_SCOPE_AGENT);
        last = (old == gridDim.x - 1);
    }
    __syncthreads();
    if (!last) return;
    // out = (1/N)*sum_t v[t]*u[t] + b2.fc_w + fc_b,  u = W2.fc_w
    float vt = __hip_atomic_load(&v[t], __ATOMIC_ACQUIRE, __HIP_MEMORY_SCOPE_AGENT);
    __shared__ float red[256];
    float u = 0.f;
#pragma unroll 4
    for (int jj = 0; jj < OUTC; jj++) u = fmaf(W2[t * OUTC + jj], fcw[jj], u);
    float contrib = vt * u * (1.0f / (float)NN);
    if (t < OUTC) contrib += b2[t] * fcw[t];
    red[t] = contrib;
    __syncthreads();
    for (int s = 128; s > 0; s >>= 1) {
        if (t < s) red[t] += red[t + s];
        __syncthreads();
    }
    if (t == 0) out[0] = red[0] + fcb[0];
}

extern "C" void kernel_launch(void* const* d_in, const int* in_sizes, int n_in,
                              void* d_out, int out_size, void* d_ws, size_t ws_size,
                              hipStream_t stream) {
    const float* x   = (const float*)d_in[0];
    const int*   ei  = (const int*)d_in[1];
    const float* W1  = (const float*)d_in[2];
    const float* b1  = (const float*)d_in[3];
    const float* W2  = (const float*)d_in[4];
    const float* b2  = (const float*)d_in[5];
    const float* fcw = (const float*)d_in[6];
    const float* fcb = (const float*)d_in[7];
    float* out = (float*)d_out;

    char* ws = (char*)d_ws;
    unsigned int*       done   = (unsigned int*)(ws + OFF_DONE);
    float*              v      = (float*)(ws + OFF_V);
    unsigned long long* flag1  = (unsigned long long*)(ws + OFF_FLAG1);
    unsigned long long* flag2  = (unsigned long long*)(ws + OFF_FLAG2);
    int*                cnt    = (int*)(ws + OFF_CNT);
    float*              dinv   = (float*)(ws + OFF_DINV);
    float*              csum   = (float*)(ws + OFF_CSUM);
    unsigned short*     ell    = (unsigned short*)(ws + OFF_ELL);
    __half*             xh     = (__half*)(ws + OFF_XH);
    __half*             xa     = (__half*)(ws + OFF_XA);
    unsigned short*     cpart  = (unsigned short*)(ws + OFF_CPART);
    float*              cspart = (float*)(ws + OFF_CSP);
    __half*             w1t    = (__half*)(ws + OFF_W1T);

    k_front<<<FRONT_B, 1024, 0, stream>>>(ei, x, W1, cpart, w1t, cnt, dinv,
                                          ell, cspart, xh, flag1, flag2,
                                          v, done);
    k_agg<<<AB + 40, 256, 0, stream>>>(x, xh, dinv, cnt, ell, cspart, csum, xa);
    k_gemm<<<GG, 256, 0, stream>>>(xa, w1t, b1, dinv, csum, v, done,
                                   W2, b2, fcw, fcb, out);
}

// Round 14
// 148.840 us; speedup vs baseline: 1.6052x; 1.0320x over previous
//
#include <hip/hip_runtime.h>
#include <hip/hip_fp16.h>

static constexpr int NN  = 10000;    // nodes
static constexpr int NE  = 640000;   // edges
static constexpr int INC = 128;
static constexpr int HIDC = 256;
static constexpr int OUTC = 128;
static constexpr int CAP = 128;      // ELL row capacity (max in-degree ~104)

static constexpr int FB = 128;       // fill/count slice blocks (5000 edges each)
static constexpr int CB = 64;        // csum slice blocks (10000 edges each)
static constexpr int HB = 313;       // half-scale blocks (1024 thr * 4 floats)
static constexpr int TB = 32;        // W1 transpose blocks (in k_count grid)
static constexpr int AB = 2500;      // agg blocks (4 nodes each)
static constexpr int NP = 10240;     // padded node stride
static constexpr int GG = 256;       // gemm blocks
static constexpr int NG = 625;       // 16-node groups

typedef _Float16 half8 __attribute__((ext_vector_type(8)));
typedef float f32x4 __attribute__((ext_vector_type(4)));

// ---- workspace layout (bytes); ws_size ~256 MB ----
static constexpr size_t OFF_DONE  = 0;          // uint[1]
static constexpr size_t OFF_V     = 64;         // float[256]
static constexpr size_t OFF_CNT   = 2048;       // int[10240]
static constexpr size_t OFF_DINV  = 43008;      // float[10240]
static constexpr size_t OFF_CSUM  = 83968;      // float[10240]
static constexpr size_t OFF_ELL   = 124928;     // ushort[10000*128] (j-permuted)
static constexpr size_t OFF_XH    = 2684928;    // half[10000*128]
static constexpr size_t OFF_XA    = 5244928;    // half[10000*128]
static constexpr size_t OFF_CPART = 7804928;    // ushort[128*10240]
static constexpr size_t OFF_CSP   = 10426368;   // float[64*10240]
static constexpr size_t OFF_W1T   = 13047808;   // half[256*128]

// ---- K1: slice-parallel degree count (LDS histogram) | W1^T transpose.
// int4 edge loads. Block 0 also zeroes v/done (consumed only by k_gemm). ----
__global__ __launch_bounds__(1024) void k_count(const int* __restrict__ ei,
                                                const float* __restrict__ W1,
                                                unsigned short* __restrict__ cpart,
                                                __half* __restrict__ w1t,
                                                float* __restrict__ v,
                                                unsigned int* __restrict__ done) {
    __shared__ int lh[NN];
    int t = threadIdx.x, b = blockIdx.x;
    if (b >= FB) {            // W1^T: 32 blocks, 256*128 entries
        int gid = (b - FB) * 1024 + t;
        int k = gid & 127, tc = gid >> 7;
        w1t[tc * INC + k] = __float2half(W1[k * HIDC + tc]);
        return;
    }
    if (b == 0) {
        if (t < 256) v[t] = 0.f;
        if (t == 256) *done = 0u;
    }
    for (int i = t; i < NN; i += 1024) lh[i] = 0;
    __syncthreads();
    int e0 = b * (NE / FB);
    const int4* d4 = (const int4*)(ei + NE + e0);
    for (int k = t; k < (NE / FB) / 4; k += 1024) {
        int4 dd = d4[k];
        atomicAdd(&lh[dd.x], 1);
        atomicAdd(&lh[dd.y], 1);
        atomicAdd(&lh[dd.z], 1);
        atomicAdd(&lh[dd.w], 1);
    }
    __syncthreads();
    for (int i = t; i < NN; i += 1024) cpart[b * NP + i] = (unsigned short)lh[i];
}

// ---- K2: per-node scan of partials -> per-block offsets, cnt, dinv.
// Coalesced: thread n reads cpart[b][n], consecutive threads contiguous. ----
__global__ __launch_bounds__(256) void k_scan(unsigned short* __restrict__ cpart,
                                              int* __restrict__ cnt,
                                              float* __restrict__ dinv) {
    int n = blockIdx.x * 256 + threadIdx.x;
    if (n >= NN) return;
    int run = 0;
#pragma unroll 8
    for (int b = 0; b < FB; b++) {
        int c = cpart[b * NP + n];
        cpart[b * NP + n] = (unsigned short)run;
        run += c;
    }
    cnt[n] = run;
    dinv[n] = rsqrtf((float)(1 + run));   // +1 self loop
}

// ---- K3 (fused): ELL fill (j-permuted, ABSOLUTE LDS cursor) | csum partials |
// fp16 X. Cursor initialized to the scan offset so atomicAdd returns the
// absolute position: one fewer LDS read per edge, and dropping soff cuts LDS
// 60->40KB => fill occupancy 2->4 blocks/CU. Proven correct in R7/R8/R11/R13.
__global__ __launch_bounds__(1024) void k_prep(const int* __restrict__ ei,
                                               const float* __restrict__ x,
                                               const float* __restrict__ dinv,
                                               const unsigned short* __restrict__ cpart,
                                               unsigned short* __restrict__ ell,
                                               float* __restrict__ cspart,
                                               __half* __restrict__ xh) {
    __shared__ int lh[NN];
    int t = threadIdx.x, b = blockIdx.x;
    if (b < FB) {
        for (int i = t; i < NN; i += 1024) lh[i] = (int)cpart[b * NP + i];
        __syncthreads();
        int e0 = b * (NE / FB);
        const int4* s4 = (const int4*)(ei + e0);
        const int4* d4 = (const int4*)(ei + NE + e0);
        for (int k = t; k < (NE / FB) / 4; k += 1024) {
            int4 s = s4[k];
            int4 d = d4[k];
            int ss[4] = {s.x, s.y, s.z, s.w};
            int dd[4] = {d.x, d.y, d.z, d.w};
#pragma unroll
            for (int u = 0; u < 4; u++) {
                int pos = atomicAdd(&lh[dd[u]], 1);   // absolute position
                if (pos < CAP)
                    ell[dd[u] * CAP + (pos & 3) * 32 + (pos >> 2)] = (unsigned short)ss[u];
            }
        }
    } else if (b < FB + CB) {
        int bb = b - FB;
        float* lc = (float*)lh;
        for (int i = t; i < NN; i += 1024) lc[i] = 0.f;
        __syncthreads();
        int e0 = bb * (NE / CB);
        const int4* s4 = (const int4*)(ei + e0);
        const int4* d4 = (const int4*)(ei + NE + e0);
        for (int k = t; k < (NE / CB) / 4; k += 1024) {
            int4 s = s4[k];
            int4 d = d4[k];
            atomicAdd(&lc[s.x], dinv[d.x]);
            atomicAdd(&lc[s.y], dinv[d.y]);
            atomicAdd(&lc[s.z], dinv[d.z]);
            atomicAdd(&lc[s.w], dinv[d.w]);
        }
        __syncthreads();
        for (int i = t; i < NN; i += 1024) cspart[bb * NP + i] = lc[i];
    } else {
        // xh[n,:] = fp16( dinv[n] * X[n,:] )
        int gid = (b - FB - CB) * 1024 + t;
        int i = gid * 4;
        if (i < NN * INC) {
            float4 vv = *(const float4*)(x + i);
            float dv = dinv[i >> 7];
            __half2 o[2] = {__floats2half2_rn(dv * vv.x, dv * vv.y),
                            __floats2half2_rn(dv * vv.z, dv * vv.w)};
            *(float2*)(xh + i) = *(float2*)o;
        }
    }
}

// ---- K4 (fused): aggregation gather | csum reduce — R6-verified body.
// Hoisted ELL loads + full/tail split; plain launch_bounds(256). ----
__global__ __launch_bounds__(256) void k_agg(const float* __restrict__ x,
                                             const __half* __restrict__ xh,
                                             const float* __restrict__ dinv,
                                             const int* __restrict__ cnt,
                                             const unsigned short* __restrict__ ell,
                                             const float* __restrict__ cspart,
                                             float* __restrict__ csum,
                                             __half* __restrict__ xa) {
    int b = blockIdx.x;
    if (b >= AB) {   // csum partial reduce (40 tail blocks)
        int n = (b - AB) * 256 + threadIdx.x;
        if (n < NN) {
            float s = 0.f;
#pragma unroll
            for (int bb = 0; bb < CB; bb++) s += cspart[bb * NP + n];
            csum[n] = s;
        }
        return;
    }
    int lane = threadIdx.x & 63;
    int n = b * 4 + (threadIdx.x >> 6);
    int g = lane & 15;        // 16B chunk of the 256B fp16 row
    int j = lane >> 4;        // neighbor group
    float dn = dinv[n];
    int c = cnt[n];
    int ebase = n * CAP + j * 32;

    uint4 ev0, ev1, ev2, ev3;
    if (c >  0) ev0 = *(const uint4*)(ell + ebase);
    if (c > 32) ev1 = *(const uint4*)(ell + ebase + 8);
    if (c > 64) ev2 = *(const uint4*)(ell + ebase + 16);
    if (c > 96) ev3 = *(const uint4*)(ell + ebase + 24);

    float acc[8];
#pragma unroll
    for (int k = 0; k < 8; k++) acc[k] = 0.f;
    if (j == 0) {             // self loop from fp32 X (outer dn applied at end)
        const float4* x4 = (const float4*)x;
        float4 a = x4[n * 32 + 2 * g];
        float4 c4 = x4[n * 32 + 2 * g + 1];
        acc[0] = dn * a.x;  acc[1] = dn * a.y;  acc[2] = dn * a.z;  acc[3] = dn * a.w;
        acc[4] = dn * c4.x; acc[5] = dn * c4.y; acc[6] = dn * c4.z; acc[7] = dn * c4.w;
    }
    const __half* xg = xh + 8 * g;
#pragma unroll
    for (int it = 0; it < 4; it++) {
        uint4 ev = (it == 0) ? ev0 : (it == 1) ? ev1 : (it == 2) ? ev2 : ev3;
        int i0 = it * 32;
        if (i0 + 32 <= c) {
            unsigned raw[8] = {ev.x & 0xffffu, ev.x >> 16, ev.y & 0xffffu, ev.y >> 16,
                               ev.z & 0xffffu, ev.z >> 16, ev.w & 0xffffu, ev.w >> 16};
            float4 xv[8];
#pragma unroll
            for (int u = 0; u < 8; u++)
                xv[u] = *(const float4*)(xg + (int)raw[u] * INC);
#pragma unroll
            for (int u = 0; u < 8; u++) {
                const __half2* h2 = (const __half2*)&xv[u];
#pragma unroll
                for (int q = 0; q < 4; q++) {
                    float2 f = __half22float2(h2[q]);
                    acc[2 * q]     += f.x;
                    acc[2 * q + 1] += f.y;
                }
            }
        } else if (i0 < c) {
            unsigned raw[8] = {ev.x & 0xffffu, ev.x >> 16, ev.y & 0xffffu, ev.y >> 16,
                               ev.z & 0xffffu, ev.z >> 16, ev.w & 0xffffu, ev.w >> 16};
            int   su[8];
            float ws[8];
            float4 xv[8];
#pragma unroll
            for (int u = 0; u < 8; u++) {
                int idx = i0 + 4 * u + j;
                bool act = idx < c;
                su[u] = act ? (int)raw[u] : n;
                ws[u] = act ? 1.f : 0.f;
            }
#pragma unroll
            for (int u = 0; u < 8; u++)
                xv[u] = *(const float4*)(xg + su[u] * INC);
#pragma unroll
            for (int u = 0; u < 8; u++) {
                const __half2* h2 = (const __half2*)&xv[u];
#pragma unroll
                for (int q = 0; q < 4; q++) {
                    float2 f = __half22float2(h2[q]);
                    acc[2 * q]     = fmaf(ws[u], f.x, acc[2 * q]);
                    acc[2 * q + 1] = fmaf(ws[u], f.y, acc[2 * q + 1]);
                }
            }
        }
    }
#pragma unroll
    for (int k = 0; k < 8; k++) {
        acc[k] += __shfl_down(acc[k], 32);
        acc[k] += __shfl_down(acc[k], 16);
    }
    if (j == 0) {
        __half2 o[4];
#pragma unroll
        for (int q = 0; q < 4; q++)
            o[q] = __floats2half2_rn(dn * acc[2 * q], dn * acc[2 * q + 1]);
        *(float4*)(xa + n * INC + 8 * g) = *(float4*)o;
    }
}

// ---- K5: MFMA GEMM + weighted-relu reduction + fused final scalar ----
__global__ __launch_bounds__(256) void k_gemm(const __half* __restrict__ xa,
                                              const __half* __restrict__ w1t,
                                              const float* __restrict__ b1,
                                              const float* __restrict__ dinv,
                                              const float* __restrict__ csum,
                                              float* __restrict__ v,
                                              unsigned int* __restrict__ done,
                                              const float* __restrict__ W2,
                                              const float* __restrict__ b2,
                                              const float* __restrict__ fcw,
                                              const float* __restrict__ fcb,
                                              float* __restrict__ out) {
    __shared__ float vloc[HIDC];
    int t = threadIdx.x;
    int w = t >> 6;           // wave id: owns cols [64w, 64w+64)
    int lane = t & 63;
    int m = lane & 15;
    int quad = lane >> 4;
    for (int i = t; i < HIDC; i += 256) vloc[i] = 0.f;
    __syncthreads();

    float bcol[4];
#pragma unroll
    for (int tt = 0; tt < 4; tt++) bcol[tt] = b1[w * 64 + tt * 16 + m];

    const half8* xa8 = (const half8*)xa;     // 8-half (16B) granules
    const half8* w8  = (const half8*)w1t;

    for (int gidx = blockIdx.x; gidx < NG; gidx += gridDim.x) {
        int base = gidx * 16;
        f32x4 acc[4] = {{0,0,0,0},{0,0,0,0},{0,0,0,0},{0,0,0,0}};
#pragma unroll
        for (int k0 = 0; k0 < 4; k0++) {
            half8 af = xa8[(base + m) * 16 + k0 * 4 + quad];
#pragma unroll
            for (int tt = 0; tt < 4; tt++) {
                int col = w * 64 + tt * 16 + m;
                half8 bf = w8[col * 16 + k0 * 4 + quad];
                acc[tt] = __builtin_amdgcn_mfma_f32_16x16x32_f16(af, bf, acc[tt], 0, 0, 0);
            }
        }
        float cr[4];
#pragma unroll
        for (int r = 0; r < 4; r++) {
            int n = base + quad * 4 + r;
            float dnn = dinv[n];
            cr[r] = dnn * (dnn + csum[n]);
        }
#pragma unroll
        for (int tt = 0; tt < 4; tt++) {
            float p = 0.f;
#pragma unroll
            for (int r = 0; r < 4; r++)
                p += cr[r] * fmaxf(acc[tt][r] + bcol[tt], 0.f);
            p += __shfl_down(p, 16);
            p += __shfl_down(p, 32);
            if (lane < 16) vloc[w * 64 + tt * 16 + lane] += p;  // wave-disjoint cols
        }
    }
    __syncthreads();
    atomicAdd(&v[t], vloc[t]);      // 256 releases: proven-cheap scale
    __threadfence();
    __shared__ bool last;
    if (t == 0) {
        unsigned int old = __hip_atomic_fetch_add(done, 1u, __ATOMIC_ACQ_REL,
                                                  __HIP_MEMORY_SCOPE_AGENT);
        last = (old == gridDim.x - 1);
    }
    __syncthreads();
    if (!last) return;
    // out = (1/N)*sum_t v[t]*u[t] + b2.fc_w + fc_b,  u = W2.fc_w
    float vt = __hip_atomic_load(&v[t], __ATOMIC_ACQUIRE, __HIP_MEMORY_SCOPE_AGENT);
    __shared__ float red[256];
    float u = 0.f;
#pragma unroll 4
    for (int jj = 0; jj < OUTC; jj++) u = fmaf(W2[t * OUTC + jj], fcw[jj], u);
    float contrib = vt * u * (1.0f / (float)NN);
    if (t < OUTC) contrib += b2[t] * fcw[t];
    red[t] = contrib;
    __syncthreads();
    for (int s = 128; s > 0; s >>= 1) {
        if (t < s) red[t] += red[t + s];
        __syncthreads();
    }
    if (t == 0) out[0] = red[0] + fcb[0];
}

extern "C" void kernel_launch(void* const* d_in, const int* in_sizes, int n_in,
                              void* d_out, int out_size, void* d_ws, size_t ws_size,
                              hipStream_t stream) {
    const float* x   = (const float*)d_in[0];
    const int*   ei  = (const int*)d_in[1];
    const float* W1  = (const float*)d_in[2];
    const float* b1  = (const float*)d_in[3];
    const float* W2  = (const float*)d_in[4];
    const float* b2  = (const float*)d_in[5];
    const float* fcw = (const float*)d_in[6];
    const float* fcb = (const float*)d_in[7];
    float* out = (float*)d_out;

    char* ws = (char*)d_ws;
    unsigned int*   done   = (unsigned int*)(ws + OFF_DONE);
    float*          v      = (float*)(ws + OFF_V);
    int*            cnt    = (int*)(ws + OFF_CNT);
    float*          dinv   = (float*)(ws + OFF_DINV);
    float*          csum   = (float*)(ws + OFF_CSUM);
    unsigned short* ell    = (unsigned short*)(ws + OFF_ELL);
    __half*         xh     = (__half*)(ws + OFF_XH);
    __half*         xa     = (__half*)(ws + OFF_XA);
    unsigned short* cpart  = (unsigned short*)(ws + OFF_CPART);
    float*          cspart = (float*)(ws + OFF_CSP);
    __half*         w1t    = (__half*)(ws + OFF_W1T);

    k_count<<<FB + TB, 1024, 0, stream>>>(ei, W1, cpart, w1t, v, done);
    k_scan<<<40, 256, 0, stream>>>(cpart, cnt, dinv);
    k_prep<<<FB + CB + HB, 1024, 0, stream>>>(ei, x, dinv, cpart, ell,
                                              cspart, xh);
    k_agg<<<AB + 40, 256, 0, stream>>>(x, xh, dinv, cnt, ell, cspart, csum, xa);
    k_gemm<<<GG, 256, 0, stream>>>(xa, w1t, b1, dinv, csum, v, done,
                                   W2, b2, fcw, fcb, out);
}